// Round 1
// baseline (202.643 us; speedup 1.0000x reference)
//
#include <hip/hip_runtime.h>
#include <hip/hip_bf16.h>
#include <stdint.h>

// ---------------------------------------------------------------------------
// Attention_47330539602252 on MI355X (gfx950). fp32 I/O, bf16 MFMA compute.
// B=8 N=1024 C=768 H=12 hd=64; quad2: t=(s*0.125+5)^2, row-normalized.
// R11 = R10 (PASS 198.6us) + ONE structural change: both GEMMs move from the
// 2-barrier full-drain 128x128/BK=32 structure (528 TF, MfmaUtil 20%) to a
// 3-slot counted-vmcnt pipeline (T4): BM=128 BN=256 BK=64, 8 waves, 144KB
// LDS, vmcnt(6) steady-state (never 0 in main loop), one raw s_barrier per
// K-step, T2 XOR chunk-swizzle on LDS reads (the attn kernel's proven
// pattern), T5 setprio around the MFMA cluster, T1 XCD-bijective block
// swizzle. Epilogues (q/k scatter, packed-V ushort4, bias) carried over.
// cvt_all and attn_quad byte-identical to R10.
// MFMA layouts (HW-verified):
//   A-frag: A[m=lane&15][k=quad*8+j]   B-frag: B[n=lane&15][k=quad*8+j]
//   C/D:    col(n)=lane&15, row(m)=quad*4+reg
// ---------------------------------------------------------------------------

typedef short  s8v  __attribute__((ext_vector_type(8)));  // 8 bf16 raw bits
typedef float  f4v  __attribute__((ext_vector_type(4)));

__device__ inline uint16_t f2bf(float f) {
    union { float f; uint32_t u; } c; c.f = f;
    uint32_t u = c.u;
    u += 0x7fffu + ((u >> 16) & 1u);   // RNE
    return (uint16_t)(u >> 16);
}
__device__ inline uint32_t pack2bf(float a, float b) {
    union { __hip_bfloat162 v; uint32_t u; } c;
    c.v = __float22bfloat162_rn(float2{a, b});   // x=a -> low 16 bits
    return c.u;
}

// async global->LDS, 16B per lane (LDS dest = wave-uniform base + lane*16)
__device__ inline void cp16(const uint16_t* g, uint16_t* l) {
    __builtin_amdgcn_global_load_lds(
        (const __attribute__((address_space(1))) void*)g,
        (__attribute__((address_space(3))) void*)l, 16, 0, 0);
}

// ---------------------------------------------------------------------------
// fp32 -> bf16 for all three inputs in one launch (dests contiguous in ws).
// ---------------------------------------------------------------------------
__global__ __launch_bounds__(256) void cvt_all(
    const float* __restrict__ x, const float* __restrict__ qw,
    const float* __restrict__ pw, uint16_t* __restrict__ dst)
{
    // totals in 8-elem groups: x 786432 | qkv_w 221184 | proj_w 73728
    int i = blockIdx.x * 256 + threadIdx.x;
    if (i >= 1081344) return;
    const float* s;
    if (i < 786432)       s = x  + (size_t)i * 8;
    else if (i < 1007616) s = qw + ((size_t)i - 786432) * 8;
    else                  s = pw + ((size_t)i - 1007616) * 8;
    const float4* sp = reinterpret_cast<const float4*>(s);
    float4 a = sp[0], b = sp[1];
    s8v o;
    o[0] = (short)f2bf(a.x); o[1] = (short)f2bf(a.y);
    o[2] = (short)f2bf(a.z); o[3] = (short)f2bf(a.w);
    o[4] = (short)f2bf(b.x); o[5] = (short)f2bf(b.y);
    o[6] = (short)f2bf(b.z); o[7] = (short)f2bf(b.w);
    *reinterpret_cast<s8v*>(dst + (size_t)i * 8) = o;
}

// ---------------------------------------------------------------------------
// Pipelined GEMM-BT: C[M,N] = A[M,K] @ Bm[N,K]^T, bf16 in, K%64==0, K>=128.
// BM=128 BN=256 BK=64. 512 threads = 8 waves (2M x 4N), wave tile 64x64
// (4x4 mfma frags). 3 LDS slots, prefetch distance 2 K-subtiles:
//   iter t top: vmcnt(6) [tile t resident; t+1's 6 loads in flight]
//               s_barrier [all waves' tile-t loads landed; tile t-1 reads done]
//               stage(t+2) into slot (t+2)%3 (= slot of t-1, now safe)
//               ds_read frags (XOR-swizzled) + 32 MFMA (setprio-wrapped)
// The ONLY vmem ops in the loop are the 6 cp16/tile, so vmcnt counts are
// exact. LDS rows are 128B, chunk-swizzled pc = lc ^ (row&7): staged via
// inverse-swizzled GLOBAL source (cp16 dest must stay linear), read with the
// same involution -> conflict-free ds_read_b128 (attn kernel's pattern).
// EPI==0: q/k scalar scatter; V packed ushort4 into [b,h,d,n].
// EPI==1: +bias, fp32 Cout[M,768].
// ---------------------------------------------------------------------------
template <int EPI>
__global__ __launch_bounds__(512, 2) void gemm_pipe(
    const uint16_t* __restrict__ A, const uint16_t* __restrict__ Bm,
    uint16_t* __restrict__ qb, uint16_t* __restrict__ kb, uint16_t* __restrict__ vb,
    const float* __restrict__ bias, float* __restrict__ Cout, int K, int GN)
{
    __shared__ uint16_t Al[3][128 * 64];   // 48 KB
    __shared__ uint16_t Bl[3][256 * 64];   // 96 KB

    const int tid  = threadIdx.x;
    const int wave = tid >> 6, lane = tid & 63;
    const int quad = lane >> 4, l16 = lane & 15;
    const int wM = wave >> 2, wN = wave & 3;

    // T1: XCD-bijective swizzle (gridDim.x % 8 == 0 for both call sites)
    const int nwg = (int)gridDim.x;
    const int wg  = ((int)blockIdx.x & 7) * (nwg >> 3) + ((int)blockIdx.x >> 3);
    const int bM = wg / GN, bN = wg - bM * GN;

    const uint16_t* Ag = A  + (size_t)bM * 128 * K;
    const uint16_t* Bg = Bm + (size_t)bN * 256 * K;

    f4v acc[4][4];
#pragma unroll
    for (int i = 0; i < 4; i++)
#pragma unroll
        for (int j = 0; j < 4; j++) { f4v z = {0.f, 0.f, 0.f, 0.f}; acc[i][j] = z; }

    const int nt = K >> 6;   // K subtiles of 64

    // stage one K-subtile into a slot: 6 cp16/thread (2 A + 4 B).
    // chunk ch: row r = ch>>3, phys chunk pc = ch&7 holds logical lc = pc^(r&7)
    auto stage = [&](int t, int slot) {
        const int kc = t << 6;
        uint16_t* as = &Al[slot][0];
        uint16_t* bs = &Bl[slot][0];
#pragma unroll
        for (int u = 0; u < 2; ++u) {
            const int ch = tid + u * 512;
            const int r  = ch >> 3, lc = (ch & 7) ^ (r & 7);
            cp16(Ag + (size_t)r * K + kc + lc * 8, as + ch * 8);
        }
#pragma unroll
        for (int u = 0; u < 4; ++u) {
            const int ch = tid + u * 512;
            const int r  = ch >> 3, lc = (ch & 7) ^ (r & 7);
            cp16(Bg + (size_t)r * K + kc + lc * 8, bs + ch * 8);
        }
    };

    auto compute = [&](int slot) {
        const uint16_t* as = &Al[slot][0];
        const uint16_t* bs = &Bl[slot][0];
        s8v af[4][2], bfr[4][2];
#pragma unroll
        for (int x = 0; x < 4; ++x) {
            const int ra = wM * 64 + x * 16 + l16;
            const int rb = wN * 64 + x * 16 + l16;
#pragma unroll
            for (int kk = 0; kk < 2; ++kk) {
                const int pa = (kk * 4 + quad) ^ (ra & 7);
                const int pb = (kk * 4 + quad) ^ (rb & 7);
                af[x][kk]  = *reinterpret_cast<const s8v*>(as + ra * 64 + pa * 8);
                bfr[x][kk] = *reinterpret_cast<const s8v*>(bs + rb * 64 + pb * 8);
            }
        }
        __builtin_amdgcn_s_setprio(1);
#pragma unroll
        for (int kk = 0; kk < 2; ++kk)
#pragma unroll
            for (int tm = 0; tm < 4; ++tm)
#pragma unroll
                for (int tn = 0; tn < 4; ++tn)
                    acc[tm][tn] = __builtin_amdgcn_mfma_f32_16x16x32_bf16(
                        af[tm][kk], bfr[tn][kk], acc[tm][tn], 0, 0, 0);
        __builtin_amdgcn_s_setprio(0);
    };

    // prologue: fill pipeline 2 deep (12 loads/thread in flight)
    stage(0, 0);
    stage(1, 1);

    int cs = 0;   // slot of tile t
    for (int t = 0; t < nt - 1; ++t) {
        asm volatile("s_waitcnt vmcnt(6)" ::: "memory");   // tile t resident
        __builtin_amdgcn_s_barrier();
        if (t + 2 < nt) {
            int ss = cs + 2; if (ss >= 3) ss -= 3;
            stage(t + 2, ss);
        }
        compute(cs);
        cs = (cs == 2) ? 0 : cs + 1;
    }
    asm volatile("s_waitcnt vmcnt(0)" ::: "memory");       // last tile
    __builtin_amdgcn_s_barrier();
    compute(cs);

    // epilogue
#pragma unroll
    for (int tm = 0; tm < 4; tm++) {
#pragma unroll
        for (int tn = 0; tn < 4; tn++) {
            const int col = bN * 256 + wN * 64 + tn * 16 + l16;
            if (EPI == 0) {
                const int three = col / 768;          // block-uniform (256 | 768)
                const int rem   = col - three * 768;
                const int h = rem >> 6, d = rem & 63;
                const int n0 = bM * 128 + wM * 64 + tm * 16 + quad * 4;
                const int b = n0 >> 10, n = n0 & 1023;   // n0%4==0: no b crossing
                if (three == 2) {
                    // V: 4 regs = 4 consecutive tokens at fixed vdim -> ushort4
                    ushort4 pk;
                    pk.x = f2bf(acc[tm][tn][0]);
                    pk.y = f2bf(acc[tm][tn][1]);
                    pk.z = f2bf(acc[tm][tn][2]);
                    pk.w = f2bf(acc[tm][tn][3]);
                    *reinterpret_cast<ushort4*>(
                        &vb[((size_t)((b * 12 + h) * 64 + d)) * 1024 + n]) = pk;
                } else {
                    uint16_t* dst = (three == 0) ? qb : kb;
#pragma unroll
                    for (int reg = 0; reg < 4; reg++)
                        dst[((size_t)((b * 12 + h) * 1024 + n + reg)) * 64 + d] =
                            f2bf(acc[tm][tn][reg]);
                }
            } else {
#pragma unroll
                for (int reg = 0; reg < 4; reg++) {
                    const int row = bM * 128 + wM * 64 + tm * 16 + quad * 4 + reg;
                    Cout[(size_t)row * 768 + col] = acc[tm][tn][reg] + bias[col];
                }
            }
        }
    }
}

// ---------------------------------------------------------------------------
// Fused quad2 attention (byte-identical to R10 PASS).
// Grid: x=8 (128 q-rows/block), y=96 (b*12+h). 2 waves; wave owns 64 q-rows
// as 4 subtiles. Per m-tile: swizzled cp16 stage of K[m][d], V^T[d][m];
// hoist K/V frags (XOR-swizzled reads); S^T = K@Q^T -> t=(s/8+5)^2 ->
// packed b64 P writes -> PV + ones-MFMA rowsum. Final O = U/rowsum.
// ---------------------------------------------------------------------------
__global__ __launch_bounds__(128, 2) void attn_quad(
    const uint16_t* __restrict__ Q, const uint16_t* __restrict__ K,
    const uint16_t* __restrict__ VT, uint16_t* __restrict__ O)
{
    const int qt = blockIdx.x;      // 0..7
    const int bh = blockIdx.y;      // 0..95
    const int b = bh / 12, h = bh - (bh / 12) * 12;
    const uint16_t* Qp = Q  + (size_t)bh * 65536;
    const uint16_t* Kp = K  + (size_t)bh * 65536;
    const uint16_t* Vp = VT + (size_t)bh * 65536;   // [d=64][n=1024]

    const int tid  = threadIdx.x;
    const int wave = tid >> 6, lane = tid & 63;
    const int quad = lane >> 4, l16 = lane & 15;

    __shared__ uint16_t Kl[64 * 64];     // [key][d], chunk-swizzled
    __shared__ uint16_t Vl[64 * 64];     // [d][m],  chunk-swizzled
    __shared__ uint16_t Pl[2][16][80];   // per-wave [qrow][m], stride 80

    // Q fragments (one-time, direct global)
    s8v qf[4][2];
#pragma unroll
    for (int s = 0; s < 4; s++) {
        const uint16_t* qp = Qp + (size_t)(qt * 128 + wave * 64 + s * 16 + l16) * 64 + quad * 8;
        qf[s][0] = *reinterpret_cast<const s8v*>(qp);
        qf[s][1] = *reinterpret_cast<const s8v*>(qp + 32);
    }

    s8v ones;
#pragma unroll
    for (int i = 0; i < 8; i++) ones[i] = (short)0x3F80;   // bf16 1.0

    f4v U[4][4], U5[4];
#pragma unroll
    for (int s = 0; s < 4; s++) {
        f4v z = {0.f, 0.f, 0.f, 0.f};
        U5[s] = z;
#pragma unroll
        for (int c = 0; c < 4; c++) U[s][c] = z;
    }

    for (int mt = 0; mt < 16; mt++) {
        __syncthreads();
        // swizzled staging: physical chunk pc of row holds logical pc^(row&7)
#pragma unroll
        for (int r = 0; r < 4; r++) {
            const int e   = (tid + r * 128) * 8;
            const int row = e >> 6;                       // key for K, d for V
            const int cl  = ((e >> 3) & 7) ^ (row & 7);   // logical chunk fetched
            cp16(Kp + (size_t)mt * 4096 + (size_t)row * 64 + cl * 8, &Kl[e]);
            cp16(Vp + (size_t)row * 1024 + mt * 64 + cl * 8, &Vl[e]);
        }
        __syncthreads();

        // hoist K/V fragments (reused by all 4 subtiles); XOR-swizzled reads
        s8v kf[4][2], vf[4][2];
#pragma unroll
        for (int c = 0; c < 4; c++) {
            const int rr = c * 16 + l16;
#pragma unroll
            for (int kk = 0; kk < 2; kk++) {
                const int pc = (kk * 4 + quad) ^ (rr & 7);
                kf[c][kk] = *reinterpret_cast<const s8v*>(&Kl[rr * 64 + (pc << 3)]);
                vf[c][kk] = *reinterpret_cast<const s8v*>(&Vl[rr * 64 + (pc << 3)]);
            }
        }

#pragma unroll
        for (int s = 0; s < 4; s++) {
            // S^T = K @ Q^T : C col=l16=qrow, row=quad*4+reg = m (in cm tile)
            f4v st[4];
#pragma unroll
            for (int cm = 0; cm < 4; cm++) {
                f4v z = {0.f, 0.f, 0.f, 0.f};
                z = __builtin_amdgcn_mfma_f32_16x16x32_bf16(kf[cm][0], qf[s][0], z, 0, 0, 0);
                z = __builtin_amdgcn_mfma_f32_16x16x32_bf16(kf[cm][1], qf[s][1], z, 0, 0, 0);
                st[cm] = z;
            }
            // t = (s*0.125+5)^2 -> packed b64 write: Pl[l16][cm*16+quad*4 ..+3]
#pragma unroll
            for (int cm = 0; cm < 4; cm++) {
                float t0 = st[cm][0] * 0.125f + 5.0f; t0 *= t0;
                float t1 = st[cm][1] * 0.125f + 5.0f; t1 *= t1;
                float t2 = st[cm][2] * 0.125f + 5.0f; t2 *= t2;
                float t3 = st[cm][3] * 0.125f + 5.0f; t3 *= t3;
                uint2 pk; pk.x = pack2bf(t0, t1); pk.y = pack2bf(t2, t3);
                *reinterpret_cast<uint2*>(&Pl[wave][l16][cm * 16 + quad * 4]) = pk;
            }
            // U += P @ V ; rowsum via ones-MFMA (same-wave DS in-order)
#pragma unroll
            for (int kc = 0; kc < 2; kc++) {
                s8v pf = *reinterpret_cast<const s8v*>(&Pl[wave][l16][kc * 32 + quad * 8]);
                U5[s] = __builtin_amdgcn_mfma_f32_16x16x32_bf16(pf, ones, U5[s], 0, 0, 0);
#pragma unroll
                for (int cd = 0; cd < 4; cd++)
                    U[s][cd] = __builtin_amdgcn_mfma_f32_16x16x32_bf16(pf, vf[cd][kc], U[s][cd], 0, 0, 0);
            }
        }
    }

    // epilogue: O[b, n, h*64+d] = U / rowsum (bf16 intermediate for proj GEMM)
#pragma unroll
    for (int s = 0; s < 4; s++) {
        float inv[4];
#pragma unroll
        for (int reg = 0; reg < 4; reg++) inv[reg] = 1.0f / U5[s][reg];
#pragma unroll
        for (int cd = 0; cd < 4; cd++) {
#pragma unroll
            for (int reg = 0; reg < 4; reg++) {
                const int n = qt * 128 + wave * 64 + s * 16 + quad * 4 + reg;
                const int d = cd * 16 + l16;
                O[((size_t)(b * 1024 + n)) * 768 + h * 64 + d] = f2bf(U[s][cd][reg] * inv[reg]);
            }
        }
    }
}

// ---------------------------------------------------------------------------
extern "C" void kernel_launch(void* const* d_in, const int* in_sizes, int n_in,
                              void* d_out, int out_size, void* d_ws, size_t ws_size,
                              hipStream_t stream)
{
    const float* x      = (const float*)d_in[0];   // [8,1024,768]
    const float* qkv_w  = (const float*)d_in[1];   // [2304,768]
    const float* proj_w = (const float*)d_in[2];   // [768,768]
    const float* proj_b = (const float*)d_in[3];   // [768]
    float* out = (float*)d_out;                    // [8,1024,768] fp32

    const size_t NEL = (size_t)8 * 1024 * 768;     // 6291456
    uint16_t* xb  = (uint16_t*)d_ws;               // bf16 x
    uint16_t* qwb = xb  + NEL;                     // bf16 qkv_w (1769472)
    uint16_t* pwb = qwb + 1769472;                 // bf16 proj_w (589824)
    uint16_t* qb  = pwb + 589824;                  // bf16 [B,H,N,64]
    uint16_t* kb  = qb  + NEL;                     // bf16 [B,H,N,64]
    uint16_t* vb  = kb  + NEL;                     // bf16 [B,H,64,N] (transposed)
    uint16_t* ao  = vb  + NEL;                     // bf16 attn out [8192,768]

    cvt_all<<<4224, 256, 0, stream>>>(x, qkv_w, proj_w, xb);

    // QKV: [8192,768] @ [2304,768]^T -> q/k scatter + V packed ushort4
    // grid 64x9 = 576 blocks (%8==0 for XCD swizzle)
    gemm_pipe<0><<<576, 512, 0, stream>>>(xb, qwb, qb, kb, vb, nullptr, nullptr, 768, 9);
    // fused quad2 attention -> ao [8192,768] bf16
    attn_quad<<<dim3(8, 96), 128, 0, stream>>>(qb, kb, vb, ao);
    // proj: [8192,768] @ [768,768]^T + bias -> fp32 out; grid 64x3 = 192
    gemm_pipe<1><<<192, 512, 0, stream>>>(ao, pwb, nullptr, nullptr, nullptr, proj_b, out, 768, 3);
}

// Round 3
// 197.807 us; speedup vs baseline: 1.0244x; 1.0244x over previous
//
#include <hip/hip_runtime.h>
#include <hip/hip_bf16.h>
#include <stdint.h>

// ---------------------------------------------------------------------------
// Attention_47330539602252 on MI355X (gfx950). fp32 I/O, bf16 MFMA compute.
// B=8 N=1024 C=768 H=12 hd=64; quad2: t=(s*0.125+5)^2, row-normalized.
// R13 = R12 resubmitted verbatim (R12's bench died to a container-acquire
// infra failure; kernel audited: uniform barriers, exact vmcnt accounting,
// slot-reuse race-free, no OOB). Structure: both GEMMs on the verified
// 8-phase cadence (T3+T4): BM=128 BN=256 BK=64, 8 waves (2Mx4N), tri-buffer
// LDS (144KB), per K-tile TWO 16-MFMA phases (split by k-half), each
// {ds_read frags; issue 3 global_load_lds; s_barrier; setprio(1); 16 MFMA;
// setprio(0); s_barrier}. Counted close-of-group vmcnt(6) (vmcnt(0) only at
// g=NT-2). Chunk-XOR swizzle kept (R11 measured 0 bank conflicts). K=768
// hardcoded. Grids: QKV 576 blocks (3 clean rounds), proj 192 (1 round).
// cvt_all and attn_quad byte-identical to R11/R10.
// MFMA layouts (HW-verified):
//   A-frag: A[m=lane&15][k=quad*8+j]   B-frag: B[n=lane&15][k=quad*8+j]
//   C/D:    col(n)=lane&15, row(m)=quad*4+reg
// ---------------------------------------------------------------------------

typedef short  s8v  __attribute__((ext_vector_type(8)));  // 8 bf16 raw bits
typedef float  f4v  __attribute__((ext_vector_type(4)));

__device__ inline uint16_t f2bf(float f) {
    union { float f; uint32_t u; } c; c.f = f;
    uint32_t u = c.u;
    u += 0x7fffu + ((u >> 16) & 1u);   // RNE
    return (uint16_t)(u >> 16);
}
__device__ inline uint32_t pack2bf(float a, float b) {
    union { __hip_bfloat162 v; uint32_t u; } c;
    c.v = __float22bfloat162_rn(float2{a, b});   // x=a -> low 16 bits
    return c.u;
}

// async global->LDS, 16B per lane (LDS dest = wave-uniform base + lane*16)
__device__ inline void cp16(const uint16_t* g, uint16_t* l) {
    __builtin_amdgcn_global_load_lds(
        (const __attribute__((address_space(1))) void*)g,
        (__attribute__((address_space(3))) void*)l, 16, 0, 0);
}

// ---------------------------------------------------------------------------
// fp32 -> bf16 for all three inputs in one launch (dests contiguous in ws).
// ---------------------------------------------------------------------------
__global__ __launch_bounds__(256) void cvt_all(
    const float* __restrict__ x, const float* __restrict__ qw,
    const float* __restrict__ pw, uint16_t* __restrict__ dst)
{
    // totals in 8-elem groups: x 786432 | qkv_w 221184 | proj_w 73728
    int i = blockIdx.x * 256 + threadIdx.x;
    if (i >= 1081344) return;
    const float* s;
    if (i < 786432)       s = x  + (size_t)i * 8;
    else if (i < 1007616) s = qw + ((size_t)i - 786432) * 8;
    else                  s = pw + ((size_t)i - 1007616) * 8;
    const float4* sp = reinterpret_cast<const float4*>(s);
    float4 a = sp[0], b = sp[1];
    s8v o;
    o[0] = (short)f2bf(a.x); o[1] = (short)f2bf(a.y);
    o[2] = (short)f2bf(a.z); o[3] = (short)f2bf(a.w);
    o[4] = (short)f2bf(b.x); o[5] = (short)f2bf(b.y);
    o[6] = (short)f2bf(b.z); o[7] = (short)f2bf(b.w);
    *reinterpret_cast<s8v*>(dst + (size_t)i * 8) = o;
}

// ---------------------------------------------------------------------------
// 8-phase GEMM-BT: C[M,N] = A[M,K=768] @ Bm[N,K=768]^T, bf16 in.
// BM=128 BN=256 BK=64, 512 threads = 8 waves (2M x 4N), wave tile 64x64
// (4x4 mfma frags). Tri-buffer LDS; group g computes K-tile g (2 phases),
// issues tile g+2's 6 loads (3 per phase) into slot (g+2)%3 (tenant g-1,
// whose reads finished before the previous group's closing barrier).
// Close of group g: vmcnt(6) ensures tile g+1 landed (the newest 6
// outstanding are tile g+2's). vmcnt(0) only at g=NT-2.
// Swizzle: physical 16B chunk pc of each 128B row holds logical pc^(row&7);
// staged via inverse-swizzled GLOBAL source (cp16 dest linear), frags read
// with the same XOR -> measured 0 bank conflicts (R11).
// EPI==0: q/k scalar scatter; V packed ushort4 into [b,h,d,n].
// EPI==1: +bias, fp32 Cout[M,768].
// ---------------------------------------------------------------------------
template <int EPI>
__global__ __launch_bounds__(512, 2) void gemm_8ph(
    const uint16_t* __restrict__ A, const uint16_t* __restrict__ Bm,
    uint16_t* __restrict__ qb, uint16_t* __restrict__ kb, uint16_t* __restrict__ vb,
    const float* __restrict__ bias, float* __restrict__ Cout, int GN)
{
    constexpr int K  = 768;
    constexpr int NT = K / 64;               // 12 K-tiles

    __shared__ uint16_t Al[3][128 * 64];     // 3 x 16 KB
    __shared__ uint16_t Bl[3][256 * 64];     // 3 x 32 KB   (total 144 KB)

    const int tid  = threadIdx.x;
    const int wave = tid >> 6, lane = tid & 63;
    const int quad = lane >> 4, l16 = lane & 15;
    const int wM = wave >> 2, wN = wave & 3;

    // T1: XCD-bijective swizzle (gridDim.x % 8 == 0 for both call sites)
    const int nwg = (int)gridDim.x;
    const int wg  = ((int)blockIdx.x & 7) * (nwg >> 3) + ((int)blockIdx.x >> 3);
    const int bM = wg / GN, bN = wg - bM * GN;

    const uint16_t* Ag = A  + (size_t)bM * 128 * K;
    const uint16_t* Bg = Bm + (size_t)bN * 256 * K;

    f4v acc[4][4];
#pragma unroll
    for (int i = 0; i < 4; i++)
#pragma unroll
        for (int j = 0; j < 4; j++) { f4v z = {0.f, 0.f, 0.f, 0.f}; acc[i][j] = z; }

    // ---- staging helpers (chunk ch: row r=ch>>3, phys chunk ch&7 holds
    //      logical lc = (ch&7)^(r&7); LDS dest linear at ch*16B) ----
    auto stA = [&](int t, int slot, int u) {
        const int ch = tid + u * 512;                 // u in {0,1}: 128 rows
        const int r  = ch >> 3, lc = (ch & 7) ^ (r & 7);
        cp16(Ag + (size_t)r * K + t * 64 + lc * 8, &Al[slot][ch * 8]);
    };
    auto stB = [&](int t, int slot, int u) {
        const int ch = tid + u * 512;                 // u in {0..3}: 256 rows
        const int r  = ch >> 3, lc = (ch & 7) ^ (r & 7);
        cp16(Bg + (size_t)r * K + t * 64 + lc * 8, &Bl[slot][ch * 8]);
    };

    // prologue: stage tiles 0,1 (12 loads in flight), confirm tile 0
    stA(0, 0, 0); stA(0, 0, 1);
    stB(0, 0, 0); stB(0, 0, 1); stB(0, 0, 2); stB(0, 0, 3);
    stA(1, 1, 0); stA(1, 1, 1);
    stB(1, 1, 0); stB(1, 1, 1); stB(1, 1, 2); stB(1, 1, 3);
    asm volatile("s_waitcnt vmcnt(6)" ::: "memory");   // tile 0 landed
    __builtin_amdgcn_s_barrier();

    int slot = 0;
    for (int g = 0; g < NT; ++g) {
        int ss = slot + 2; if (ss >= 3) ss -= 3;       // slot of tile g+2
        const bool pf = (g + 2 < NT);
        const uint16_t* as = &Al[slot][0];
        const uint16_t* bs = &Bl[slot][0];

        // ================= phase 0 : kk = 0 =================
        s8v af[4], bq[4];
#pragma unroll
        for (int x = 0; x < 4; ++x) {
            const int ra = wM * 64 + x * 16 + l16;
            const int pa = quad ^ (ra & 7);            // kk=0
            af[x] = *reinterpret_cast<const s8v*>(as + ra * 64 + pa * 8);
        }
#pragma unroll
        for (int x = 0; x < 4; ++x) {
            const int rb = wN * 64 + x * 16 + l16;
            const int pb = quad ^ (rb & 7);
            bq[x] = *reinterpret_cast<const s8v*>(bs + rb * 64 + pb * 8);
        }
        if (pf) { stA(g + 2, ss, 0); stA(g + 2, ss, 1); stB(g + 2, ss, 0); }
        __builtin_amdgcn_s_barrier();
        __builtin_amdgcn_s_setprio(1);
#pragma unroll
        for (int tm = 0; tm < 4; ++tm)
#pragma unroll
            for (int tn = 0; tn < 4; ++tn)
                acc[tm][tn] = __builtin_amdgcn_mfma_f32_16x16x32_bf16(
                    af[tm], bq[tn], acc[tm][tn], 0, 0, 0);
        __builtin_amdgcn_s_setprio(0);
        __builtin_amdgcn_s_barrier();

        // ================= phase 1 : kk = 1 =================
#pragma unroll
        for (int x = 0; x < 4; ++x) {
            const int ra = wM * 64 + x * 16 + l16;
            const int pa = (4 + quad) ^ (ra & 7);      // kk=1
            af[x] = *reinterpret_cast<const s8v*>(as + ra * 64 + pa * 8);
        }
#pragma unroll
        for (int x = 0; x < 4; ++x) {
            const int rb = wN * 64 + x * 16 + l16;
            const int pb = (4 + quad) ^ (rb & 7);
            bq[x] = *reinterpret_cast<const s8v*>(bs + rb * 64 + pb * 8);
        }
        if (pf) { stB(g + 2, ss, 1); stB(g + 2, ss, 2); stB(g + 2, ss, 3); }
        __builtin_amdgcn_s_barrier();
        __builtin_amdgcn_s_setprio(1);
#pragma unroll
        for (int tm = 0; tm < 4; ++tm)
#pragma unroll
            for (int tn = 0; tn < 4; ++tn)
                acc[tm][tn] = __builtin_amdgcn_mfma_f32_16x16x32_bf16(
                    af[tm], bq[tn], acc[tm][tn], 0, 0, 0);
        __builtin_amdgcn_s_setprio(0);

        // close of group: confirm tile g+1 before next group's ds_reads.
        if (g < NT - 2)       asm volatile("s_waitcnt vmcnt(6)" ::: "memory");
        else if (g == NT - 2) asm volatile("s_waitcnt vmcnt(0)" ::: "memory");
        if (g < NT - 1) __builtin_amdgcn_s_barrier();

        slot = (slot == 2) ? 0 : slot + 1;
    }

    // epilogue (identical scatter logic to R11, BN=256)
#pragma unroll
    for (int tm = 0; tm < 4; tm++) {
#pragma unroll
        for (int tn = 0; tn < 4; tn++) {
            const int col = bN * 256 + wN * 64 + tn * 16 + l16;
            if (EPI == 0) {
                const int three = col / 768;          // block-uniform (256 | 768)
                const int rem   = col - three * 768;
                const int h = rem >> 6, d = rem & 63;
                const int n0 = bM * 128 + wM * 64 + tm * 16 + quad * 4;
                const int b = n0 >> 10, n = n0 & 1023;   // n0%4==0: no b crossing
                if (three == 2) {
                    // V: 4 regs = 4 consecutive tokens at fixed vdim -> ushort4
                    ushort4 pk;
                    pk.x = f2bf(acc[tm][tn][0]);
                    pk.y = f2bf(acc[tm][tn][1]);
                    pk.z = f2bf(acc[tm][tn][2]);
                    pk.w = f2bf(acc[tm][tn][3]);
                    *reinterpret_cast<ushort4*>(
                        &vb[((size_t)((b * 12 + h) * 64 + d)) * 1024 + n]) = pk;
                } else {
                    uint16_t* dst = (three == 0) ? qb : kb;
#pragma unroll
                    for (int reg = 0; reg < 4; reg++)
                        dst[((size_t)((b * 12 + h) * 1024 + n + reg)) * 64 + d] =
                            f2bf(acc[tm][tn][reg]);
                }
            } else {
#pragma unroll
                for (int reg = 0; reg < 4; reg++) {
                    const int row = bM * 128 + wM * 64 + tm * 16 + quad * 4 + reg;
                    Cout[(size_t)row * 768 + col] = acc[tm][tn][reg] + bias[col];
                }
            }
        }
    }
}

// ---------------------------------------------------------------------------
// Fused quad2 attention (byte-identical to R10/R11 PASS).
// Grid: x=8 (128 q-rows/block), y=96 (b*12+h). 2 waves; wave owns 64 q-rows
// as 4 subtiles. Per m-tile: swizzled cp16 stage of K[m][d], V^T[d][m];
// hoist K/V frags (XOR-swizzled reads); S^T = K@Q^T -> t=(s/8+5)^2 ->
// packed b64 P writes -> PV + ones-MFMA rowsum. Final O = U/rowsum.
// ---------------------------------------------------------------------------
__global__ __launch_bounds__(128, 2) void attn_quad(
    const uint16_t* __restrict__ Q, const uint16_t* __restrict__ K,
    const uint16_t* __restrict__ VT, uint16_t* __restrict__ O)
{
    const int qt = blockIdx.x;      // 0..7
    const int bh = blockIdx.y;      // 0..95
    const int b = bh / 12, h = bh - (bh / 12) * 12;
    const uint16_t* Qp = Q  + (size_t)bh * 65536;
    const uint16_t* Kp = K  + (size_t)bh * 65536;
    const uint16_t* Vp = VT + (size_t)bh * 65536;   // [d=64][n=1024]

    const int tid  = threadIdx.x;
    const int wave = tid >> 6, lane = tid & 63;
    const int quad = lane >> 4, l16 = lane & 15;

    __shared__ uint16_t Kl[64 * 64];     // [key][d], chunk-swizzled
    __shared__ uint16_t Vl[64 * 64];     // [d][m],  chunk-swizzled
    __shared__ uint16_t Pl[2][16][80];   // per-wave [qrow][m], stride 80

    // Q fragments (one-time, direct global)
    s8v qf[4][2];
#pragma unroll
    for (int s = 0; s < 4; s++) {
        const uint16_t* qp = Qp + (size_t)(qt * 128 + wave * 64 + s * 16 + l16) * 64 + quad * 8;
        qf[s][0] = *reinterpret_cast<const s8v*>(qp);
        qf[s][1] = *reinterpret_cast<const s8v*>(qp + 32);
    }

    s8v ones;
#pragma unroll
    for (int i = 0; i < 8; i++) ones[i] = (short)0x3F80;   // bf16 1.0

    f4v U[4][4], U5[4];
#pragma unroll
    for (int s = 0; s < 4; s++) {
        f4v z = {0.f, 0.f, 0.f, 0.f};
        U5[s] = z;
#pragma unroll
        for (int c = 0; c < 4; c++) U[s][c] = z;
    }

    for (int mt = 0; mt < 16; mt++) {
        __syncthreads();
        // swizzled staging: physical chunk pc of row holds logical pc^(row&7)
#pragma unroll
        for (int r = 0; r < 4; r++) {
            const int e   = (tid + r * 128) * 8;
            const int row = e >> 6;                       // key for K, d for V
            const int cl  = ((e >> 3) & 7) ^ (row & 7);   // logical chunk fetched
            cp16(Kp + (size_t)mt * 4096 + (size_t)row * 64 + cl * 8, &Kl[e]);
            cp16(Vp + (size_t)row * 1024 + mt * 64 + cl * 8, &Vl[e]);
        }
        __syncthreads();

        // hoist K/V fragments (reused by all 4 subtiles); XOR-swizzled reads
        s8v kf[4][2], vf[4][2];
#pragma unroll
        for (int c = 0; c < 4; c++) {
            const int rr = c * 16 + l16;
#pragma unroll
            for (int kk = 0; kk < 2; kk++) {
                const int pc = (kk * 4 + quad) ^ (rr & 7);
                kf[c][kk] = *reinterpret_cast<const s8v*>(&Kl[rr * 64 + (pc << 3)]);
                vf[c][kk] = *reinterpret_cast<const s8v*>(&Vl[rr * 64 + (pc << 3)]);
            }
        }

#pragma unroll
        for (int s = 0; s < 4; s++) {
            // S^T = K @ Q^T : C col=l16=qrow, row=quad*4+reg = m (in cm tile)
            f4v st[4];
#pragma unroll
            for (int cm = 0; cm < 4; cm++) {
                f4v z = {0.f, 0.f, 0.f, 0.f};
                z = __builtin_amdgcn_mfma_f32_16x16x32_bf16(kf[cm][0], qf[s][0], z, 0, 0, 0);
                z = __builtin_amdgcn_mfma_f32_16x16x32_bf16(kf[cm][1], qf[s][1], z, 0, 0, 0);
                st[cm] = z;
            }
            // t = (s*0.125+5)^2 -> packed b64 write: Pl[l16][cm*16+quad*4 ..+3]
#pragma unroll
            for (int cm = 0; cm < 4; cm++) {
                float t0 = st[cm][0] * 0.125f + 5.0f; t0 *= t0;
                float t1 = st[cm][1] * 0.125f + 5.0f; t1 *= t1;
                float t2 = st[cm][2] * 0.125f + 5.0f; t2 *= t2;
                float t3 = st[cm][3] * 0.125f + 5.0f; t3 *= t3;
                uint2 pk; pk.x = pack2bf(t0, t1); pk.y = pack2bf(t2, t3);
                *reinterpret_cast<uint2*>(&Pl[wave][l16][cm * 16 + quad * 4]) = pk;
            }
            // U += P @ V ; rowsum via ones-MFMA (same-wave DS in-order)
#pragma unroll
            for (int kc = 0; kc < 2; kc++) {
                s8v pf = *reinterpret_cast<const s8v*>(&Pl[wave][l16][kc * 32 + quad * 8]);
                U5[s] = __builtin_amdgcn_mfma_f32_16x16x32_bf16(pf, ones, U5[s], 0, 0, 0);
#pragma unroll
                for (int cd = 0; cd < 4; cd++)
                    U[s][cd] = __builtin_amdgcn_mfma_f32_16x16x32_bf16(pf, vf[cd][kc], U[s][cd], 0, 0, 0);
            }
        }
    }

    // epilogue: O[b, n, h*64+d] = U / rowsum (bf16 intermediate for proj GEMM)
#pragma unroll
    for (int s = 0; s < 4; s++) {
        float inv[4];
#pragma unroll
        for (int reg = 0; reg < 4; reg++) inv[reg] = 1.0f / U5[s][reg];
#pragma unroll
        for (int cd = 0; cd < 4; cd++) {
#pragma unroll
            for (int reg = 0; reg < 4; reg++) {
                const int n = qt * 128 + wave * 64 + s * 16 + quad * 4 + reg;
                const int d = cd * 16 + l16;
                O[((size_t)(b * 1024 + n)) * 768 + h * 64 + d] = f2bf(U[s][cd][reg] * inv[reg]);
            }
        }
    }
}

// ---------------------------------------------------------------------------
extern "C" void kernel_launch(void* const* d_in, const int* in_sizes, int n_in,
                              void* d_out, int out_size, void* d_ws, size_t ws_size,
                              hipStream_t stream)
{
    const float* x      = (const float*)d_in[0];   // [8,1024,768]
    const float* qkv_w  = (const float*)d_in[1];   // [2304,768]
    const float* proj_w = (const float*)d_in[2];   // [768,768]
    const float* proj_b = (const float*)d_in[3];   // [768]
    float* out = (float*)d_out;                    // [8,1024,768] fp32

    const size_t NEL = (size_t)8 * 1024 * 768;     // 6291456
    uint16_t* xb  = (uint16_t*)d_ws;               // bf16 x
    uint16_t* qwb = xb  + NEL;                     // bf16 qkv_w (1769472)
    uint16_t* pwb = qwb + 1769472;                 // bf16 proj_w (589824)
    uint16_t* qb  = pwb + 589824;                  // bf16 [B,H,N,64]
    uint16_t* kb  = qb  + NEL;                     // bf16 [B,H,N,64]
    uint16_t* vb  = kb  + NEL;                     // bf16 [B,H,64,N] (transposed)
    uint16_t* ao  = vb  + NEL;                     // bf16 attn out [8192,768]

    cvt_all<<<4224, 256, 0, stream>>>(x, qkv_w, proj_w, xb);

    // QKV: [8192,768] @ [2304,768]^T -> q/k scatter + V packed ushort4
    // grid 64x9 = 576 blocks (3 clean rounds; %8==0 for XCD swizzle)
    gemm_8ph<0><<<576, 512, 0, stream>>>(xb, qwb, qb, kb, vb, nullptr, nullptr, 9);
    // fused quad2 attention -> ao [8192,768] bf16
    attn_quad<<<dim3(8, 96), 128, 0, stream>>>(qb, kb, vb, ao);
    // proj: [8192,768] @ [768,768]^T + bias -> fp32 out; grid 64x3 = 192
    gemm_8ph<1><<<192, 512, 0, stream>>>(ao, pwb, nullptr, nullptr, nullptr, proj_b, out, 3);
}

// Round 4
// 186.788 us; speedup vs baseline: 1.0849x; 1.0590x over previous
//
#include <hip/hip_runtime.h>
#include <hip/hip_bf16.h>
#include <stdint.h>

// ---------------------------------------------------------------------------
// Attention_47330539602252 on MI355X (gfx950). fp32 I/O, bf16 MFMA compute.
// B=8 N=1024 C=768 H=12 hd=64; quad2: t=(s*0.125+5)^2, row-normalized.
// R14: GEMMs ported to the m97-faithful structure (the 912-TF-verified one):
// 128x128 tile, BK=64, 256 threads = 4 waves (2x2), SINGLE-buffer 32KB LDS,
// two __syncthreads per K-step, width-16 global_load_lds staging, XOR
// chunk-swizzled LDS (staged via inverse-swizzled global source, read with
// same XOR; measured 0 conflicts in R11/R13). No setprio (m190: null in
// lockstep GEMM). Relies on multi-block TLP (3-5 blocks/CU at 32KB LDS) to
// mask the barrier drain — the thing R11/R13's 144KB 1-block/CU variants
// lacked. XCD-bijective block swizzle kept (1152/384 blocks, %8==0).
// Epilogues (q/k scatter, packed-V ushort4, bias) carried over unchanged.
// cvt_all and attn_quad byte-identical to R10/R11/R13.
// MFMA layouts (HW-verified):
//   A-frag: A[m=lane&15][k=quad*8+j]   B-frag: B[n=lane&15][k=quad*8+j]
//   C/D:    col(n)=lane&15, row(m)=quad*4+reg
// ---------------------------------------------------------------------------

typedef short  s8v  __attribute__((ext_vector_type(8)));  // 8 bf16 raw bits
typedef float  f4v  __attribute__((ext_vector_type(4)));

__device__ inline uint16_t f2bf(float f) {
    union { float f; uint32_t u; } c; c.f = f;
    uint32_t u = c.u;
    u += 0x7fffu + ((u >> 16) & 1u);   // RNE
    return (uint16_t)(u >> 16);
}
__device__ inline uint32_t pack2bf(float a, float b) {
    union { __hip_bfloat162 v; uint32_t u; } c;
    c.v = __float22bfloat162_rn(float2{a, b});   // x=a -> low 16 bits
    return c.u;
}

// async global->LDS, 16B per lane (LDS dest = wave-uniform base + lane*16)
__device__ inline void cp16(const uint16_t* g, uint16_t* l) {
    __builtin_amdgcn_global_load_lds(
        (const __attribute__((address_space(1))) void*)g,
        (__attribute__((address_space(3))) void*)l, 16, 0, 0);
}

// ---------------------------------------------------------------------------
// fp32 -> bf16 for all three inputs in one launch (dests contiguous in ws).
// ---------------------------------------------------------------------------
__global__ __launch_bounds__(256) void cvt_all(
    const float* __restrict__ x, const float* __restrict__ qw,
    const float* __restrict__ pw, uint16_t* __restrict__ dst)
{
    // totals in 8-elem groups: x 786432 | qkv_w 221184 | proj_w 73728
    int i = blockIdx.x * 256 + threadIdx.x;
    if (i >= 1081344) return;
    const float* s;
    if (i < 786432)       s = x  + (size_t)i * 8;
    else if (i < 1007616) s = qw + ((size_t)i - 786432) * 8;
    else                  s = pw + ((size_t)i - 1007616) * 8;
    const float4* sp = reinterpret_cast<const float4*>(s);
    float4 a = sp[0], b = sp[1];
    s8v o;
    o[0] = (short)f2bf(a.x); o[1] = (short)f2bf(a.y);
    o[2] = (short)f2bf(a.z); o[3] = (short)f2bf(a.w);
    o[4] = (short)f2bf(b.x); o[5] = (short)f2bf(b.y);
    o[6] = (short)f2bf(b.z); o[7] = (short)f2bf(b.w);
    *reinterpret_cast<s8v*>(dst + (size_t)i * 8) = o;
}

// ---------------------------------------------------------------------------
// m97-structure GEMM-BT: C[M,N] = A[M,K=768] @ Bm[N,K=768]^T, bf16 in.
// BM=BN=128, BK=64. 256 threads = 4 waves (2Mx2N), wave tile 64x64 (4x4
// mfma frags, 32 MFMA per K-step). Single-buffer LDS 32KB -> multiple
// blocks/CU; per K-step: sync; 8 cp16/thread; sync; 16 ds_read_b128 frags;
// 32 MFMA. Barrier drain masked by co-resident blocks (m114).
// Swizzle: phys 16B chunk pc of each 128B row holds logical pc^(row&7).
// EPI==0: q/k scalar scatter; V packed ushort4 into [b,h,d,n].
// EPI==1: +bias, fp32 Cout[M,768].
// ---------------------------------------------------------------------------
template <int EPI>
__global__ __launch_bounds__(256) void gemm_m97(
    const uint16_t* __restrict__ A, const uint16_t* __restrict__ Bm,
    uint16_t* __restrict__ qb, uint16_t* __restrict__ kb, uint16_t* __restrict__ vb,
    const float* __restrict__ bias, float* __restrict__ Cout, int GN)
{
    constexpr int K  = 768;
    constexpr int NT = K / 64;               // 12 K-steps

    __shared__ uint16_t Al[128 * 64];        // 16 KB
    __shared__ uint16_t Bl[128 * 64];        // 16 KB

    const int tid  = threadIdx.x;
    const int wave = tid >> 6, lane = tid & 63;
    const int quad = lane >> 4, l16 = lane & 15;
    const int wM = wave >> 1, wN = wave & 1;

    // T1: XCD-bijective swizzle (gridDim.x % 8 == 0 for both call sites)
    const int nwg = (int)gridDim.x;
    const int wg  = ((int)blockIdx.x & 7) * (nwg >> 3) + ((int)blockIdx.x >> 3);
    const int bM = wg / GN, bN = wg - bM * GN;

    const uint16_t* Ag = A  + (size_t)bM * 128 * K;
    const uint16_t* Bg = Bm + (size_t)bN * 128 * K;

    f4v acc[4][4];
#pragma unroll
    for (int i = 0; i < 4; i++)
#pragma unroll
        for (int j = 0; j < 4; j++) { f4v z = {0.f, 0.f, 0.f, 0.f}; acc[i][j] = z; }

    for (int t = 0; t < NT; ++t) {
        __syncthreads();
        // stage 128x64 A and B, 4 chunks each per thread (8 cp16).
        // chunk ch: row r=ch>>3; phys chunk ch&7 holds logical lc=(ch&7)^(r&7)
#pragma unroll
        for (int u = 0; u < 4; ++u) {
            const int ch = tid + u * 256;
            const int r  = ch >> 3, lc = (ch & 7) ^ (r & 7);
            cp16(Ag + (size_t)r * K + t * 64 + lc * 8, &Al[ch * 8]);
        }
#pragma unroll
        for (int u = 0; u < 4; ++u) {
            const int ch = tid + u * 256;
            const int r  = ch >> 3, lc = (ch & 7) ^ (r & 7);
            cp16(Bg + (size_t)r * K + t * 64 + lc * 8, &Bl[ch * 8]);
        }
        __syncthreads();

        // fragments (XOR-swizzled reads; R11/R13 measured 0 bank conflicts)
        s8v af[4][2], bq[4][2];
#pragma unroll
        for (int x = 0; x < 4; ++x) {
            const int ra = wM * 64 + x * 16 + l16;
            const int rb = wN * 64 + x * 16 + l16;
#pragma unroll
            for (int kk = 0; kk < 2; ++kk) {
                const int pa = (kk * 4 + quad) ^ (ra & 7);
                const int pb = (kk * 4 + quad) ^ (rb & 7);
                af[x][kk] = *reinterpret_cast<const s8v*>(&Al[ra * 64 + pa * 8]);
                bq[x][kk] = *reinterpret_cast<const s8v*>(&Bl[rb * 64 + pb * 8]);
            }
        }
#pragma unroll
        for (int kk = 0; kk < 2; ++kk)
#pragma unroll
            for (int tm = 0; tm < 4; ++tm)
#pragma unroll
                for (int tn = 0; tn < 4; ++tn)
                    acc[tm][tn] = __builtin_amdgcn_mfma_f32_16x16x32_bf16(
                        af[tm][kk], bq[tn][kk], acc[tm][tn], 0, 0, 0);
    }

    // epilogue (identical scatter logic; BN=128)
#pragma unroll
    for (int tm = 0; tm < 4; tm++) {
#pragma unroll
        for (int tn = 0; tn < 4; tn++) {
            const int col = bN * 128 + wN * 64 + tn * 16 + l16;
            if (EPI == 0) {
                const int three = col / 768;          // block-uniform (128 | 768)
                const int rem   = col - three * 768;
                const int h = rem >> 6, d = rem & 63;
                const int n0 = bM * 128 + wM * 64 + tm * 16 + quad * 4;
                const int b = n0 >> 10, n = n0 & 1023;   // n0%4==0: no b crossing
                if (three == 2) {
                    // V: 4 regs = 4 consecutive tokens at fixed vdim -> ushort4
                    ushort4 pk;
                    pk.x = f2bf(acc[tm][tn][0]);
                    pk.y = f2bf(acc[tm][tn][1]);
                    pk.z = f2bf(acc[tm][tn][2]);
                    pk.w = f2bf(acc[tm][tn][3]);
                    *reinterpret_cast<ushort4*>(
                        &vb[((size_t)((b * 12 + h) * 64 + d)) * 1024 + n]) = pk;
                } else {
                    uint16_t* dst = (three == 0) ? qb : kb;
#pragma unroll
                    for (int reg = 0; reg < 4; reg++)
                        dst[((size_t)((b * 12 + h) * 1024 + n + reg)) * 64 + d] =
                            f2bf(acc[tm][tn][reg]);
                }
            } else {
#pragma unroll
                for (int reg = 0; reg < 4; reg++) {
                    const int row = bM * 128 + wM * 64 + tm * 16 + quad * 4 + reg;
                    Cout[(size_t)row * 768 + col] = acc[tm][tn][reg] + bias[col];
                }
            }
        }
    }
}

// ---------------------------------------------------------------------------
// Fused quad2 attention (byte-identical to R10/R11/R13 PASS).
// Grid: x=8 (128 q-rows/block), y=96 (b*12+h). 2 waves; wave owns 64 q-rows
// as 4 subtiles. Per m-tile: swizzled cp16 stage of K[m][d], V^T[d][m];
// hoist K/V frags (XOR-swizzled reads); S^T = K@Q^T -> t=(s/8+5)^2 ->
// packed b64 P writes -> PV + ones-MFMA rowsum. Final O = U/rowsum.
// ---------------------------------------------------------------------------
__global__ __launch_bounds__(128, 2) void attn_quad(
    const uint16_t* __restrict__ Q, const uint16_t* __restrict__ K,
    const uint16_t* __restrict__ VT, uint16_t* __restrict__ O)
{
    const int qt = blockIdx.x;      // 0..7
    const int bh = blockIdx.y;      // 0..95
    const int b = bh / 12, h = bh - (bh / 12) * 12;
    const uint16_t* Qp = Q  + (size_t)bh * 65536;
    const uint16_t* Kp = K  + (size_t)bh * 65536;
    const uint16_t* Vp = VT + (size_t)bh * 65536;   // [d=64][n=1024]

    const int tid  = threadIdx.x;
    const int wave = tid >> 6, lane = tid & 63;
    const int quad = lane >> 4, l16 = lane & 15;

    __shared__ uint16_t Kl[64 * 64];     // [key][d], chunk-swizzled
    __shared__ uint16_t Vl[64 * 64];     // [d][m],  chunk-swizzled
    __shared__ uint16_t Pl[2][16][80];   // per-wave [qrow][m], stride 80

    // Q fragments (one-time, direct global)
    s8v qf[4][2];
#pragma unroll
    for (int s = 0; s < 4; s++) {
        const uint16_t* qp = Qp + (size_t)(qt * 128 + wave * 64 + s * 16 + l16) * 64 + quad * 8;
        qf[s][0] = *reinterpret_cast<const s8v*>(qp);
        qf[s][1] = *reinterpret_cast<const s8v*>(qp + 32);
    }

    s8v ones;
#pragma unroll
    for (int i = 0; i < 8; i++) ones[i] = (short)0x3F80;   // bf16 1.0

    f4v U[4][4], U5[4];
#pragma unroll
    for (int s = 0; s < 4; s++) {
        f4v z = {0.f, 0.f, 0.f, 0.f};
        U5[s] = z;
#pragma unroll
        for (int c = 0; c < 4; c++) U[s][c] = z;
    }

    for (int mt = 0; mt < 16; mt++) {
        __syncthreads();
        // swizzled staging: physical chunk pc of row holds logical pc^(row&7)
#pragma unroll
        for (int r = 0; r < 4; r++) {
            const int e   = (tid + r * 128) * 8;
            const int row = e >> 6;                       // key for K, d for V
            const int cl  = ((e >> 3) & 7) ^ (row & 7);   // logical chunk fetched
            cp16(Kp + (size_t)mt * 4096 + (size_t)row * 64 + cl * 8, &Kl[e]);
            cp16(Vp + (size_t)row * 1024 + mt * 64 + cl * 8, &Vl[e]);
        }
        __syncthreads();

        // hoist K/V fragments (reused by all 4 subtiles); XOR-swizzled reads
        s8v kf[4][2], vf[4][2];
#pragma unroll
        for (int c = 0; c < 4; c++) {
            const int rr = c * 16 + l16;
#pragma unroll
            for (int kk = 0; kk < 2; kk++) {
                const int pc = (kk * 4 + quad) ^ (rr & 7);
                kf[c][kk] = *reinterpret_cast<const s8v*>(&Kl[rr * 64 + (pc << 3)]);
                vf[c][kk] = *reinterpret_cast<const s8v*>(&Vl[rr * 64 + (pc << 3)]);
            }
        }

#pragma unroll
        for (int s = 0; s < 4; s++) {
            // S^T = K @ Q^T : C col=l16=qrow, row=quad*4+reg = m (in cm tile)
            f4v st[4];
#pragma unroll
            for (int cm = 0; cm < 4; cm++) {
                f4v z = {0.f, 0.f, 0.f, 0.f};
                z = __builtin_amdgcn_mfma_f32_16x16x32_bf16(kf[cm][0], qf[s][0], z, 0, 0, 0);
                z = __builtin_amdgcn_mfma_f32_16x16x32_bf16(kf[cm][1], qf[s][1], z, 0, 0, 0);
                st[cm] = z;
            }
            // t = (s*0.125+5)^2 -> packed b64 write: Pl[l16][cm*16+quad*4 ..+3]
#pragma unroll
            for (int cm = 0; cm < 4; cm++) {
                float t0 = st[cm][0] * 0.125f + 5.0f; t0 *= t0;
                float t1 = st[cm][1] * 0.125f + 5.0f; t1 *= t1;
                float t2 = st[cm][2] * 0.125f + 5.0f; t2 *= t2;
                float t3 = st[cm][3] * 0.125f + 5.0f; t3 *= t3;
                uint2 pk; pk.x = pack2bf(t0, t1); pk.y = pack2bf(t2, t3);
                *reinterpret_cast<uint2*>(&Pl[wave][l16][cm * 16 + quad * 4]) = pk;
            }
            // U += P @ V ; rowsum via ones-MFMA (same-wave DS in-order)
#pragma unroll
            for (int kc = 0; kc < 2; kc++) {
                s8v pf = *reinterpret_cast<const s8v*>(&Pl[wave][l16][kc * 32 + quad * 8]);
                U5[s] = __builtin_amdgcn_mfma_f32_16x16x32_bf16(pf, ones, U5[s], 0, 0, 0);
#pragma unroll
                for (int cd = 0; cd < 4; cd++)
                    U[s][cd] = __builtin_amdgcn_mfma_f32_16x16x32_bf16(pf, vf[cd][kc], U[s][cd], 0, 0, 0);
            }
        }
    }

    // epilogue: O[b, n, h*64+d] = U / rowsum (bf16 intermediate for proj GEMM)
#pragma unroll
    for (int s = 0; s < 4; s++) {
        float inv[4];
#pragma unroll
        for (int reg = 0; reg < 4; reg++) inv[reg] = 1.0f / U5[s][reg];
#pragma unroll
        for (int cd = 0; cd < 4; cd++) {
#pragma unroll
            for (int reg = 0; reg < 4; reg++) {
                const int n = qt * 128 + wave * 64 + s * 16 + quad * 4 + reg;
                const int d = cd * 16 + l16;
                O[((size_t)(b * 1024 + n)) * 768 + h * 64 + d] = f2bf(U[s][cd][reg] * inv[reg]);
            }
        }
    }
}

// ---------------------------------------------------------------------------
extern "C" void kernel_launch(void* const* d_in, const int* in_sizes, int n_in,
                              void* d_out, int out_size, void* d_ws, size_t ws_size,
                              hipStream_t stream)
{
    const float* x      = (const float*)d_in[0];   // [8,1024,768]
    const float* qkv_w  = (const float*)d_in[1];   // [2304,768]
    const float* proj_w = (const float*)d_in[2];   // [768,768]
    const float* proj_b = (const float*)d_in[3];   // [768]
    float* out = (float*)d_out;                    // [8,1024,768] fp32

    const size_t NEL = (size_t)8 * 1024 * 768;     // 6291456
    uint16_t* xb  = (uint16_t*)d_ws;               // bf16 x
    uint16_t* qwb = xb  + NEL;                     // bf16 qkv_w (1769472)
    uint16_t* pwb = qwb + 1769472;                 // bf16 proj_w (589824)
    uint16_t* qb  = pwb + 589824;                  // bf16 [B,H,N,64]
    uint16_t* kb  = qb  + NEL;                     // bf16 [B,H,N,64]
    uint16_t* vb  = kb  + NEL;                     // bf16 [B,H,64,N] (transposed)
    uint16_t* ao  = vb  + NEL;                     // bf16 attn out [8192,768]

    cvt_all<<<4224, 256, 0, stream>>>(x, qkv_w, proj_w, xb);

    // QKV: [8192,768] @ [2304,768]^T -> q/k scatter + V packed ushort4
    // grid 64x18 = 1152 blocks (%8==0 for XCD swizzle); 32KB LDS -> multi
    // blocks/CU for implicit barrier-drain masking (m114)
    gemm_m97<0><<<1152, 256, 0, stream>>>(xb, qwb, qb, kb, vb, nullptr, nullptr, 18);
    // fused quad2 attention -> ao [8192,768] bf16
    attn_quad<<<dim3(8, 96), 128, 0, stream>>>(qb, kb, vb, ao);
    // proj: [8192,768] @ [768,768]^T + bias -> fp32 out; grid 64x6 = 384
    gemm_m97<1><<<384, 256, 0, stream>>>(ao, pwb, nullptr, nullptr, nullptr, proj_b, out, 6);
}